// Round 1
// 110.949 us; speedup vs baseline: 1.0587x; 1.0587x over previous
//
#include <hip/hip_runtime.h>
#include <math.h>

// Problem constants
constexpr int NN = 1024;   // nodes
constexpr int DD = 256;    // embedding dim
constexpr int HH = 128;    // hidden dim
constexpr float BN_EPS = 1e-5f;

// Workspace layout (in floats)
constexpr int OFF_A      = 0;                          // [1024 x 1024] adjacency
constexpr int OFF_AP     = OFF_A + NN * NN;            // [N x H] a + b1
constexpr int OFF_CP     = OFF_AP + NN * HH;           // [N x H] c
constexpr int OFF_Y      = OFF_CP + NN * HH;           // [N x H] X@Wg
constexpr int OFF_DEG    = OFF_Y + NN * HH;            // [N] degree accumulators
constexpr int OFF_P0     = OFF_DEG + NN;               // [H x N] partial (j-half 0), TRANSPOSED
constexpr int OFF_P1     = OFF_P0 + NN * HH;           // [H x N] partial (j-half 1), TRANSPOSED

// ---------------------------------------------------------------------------
// K1: fused GEMMs  aP = X@W1[:D]+b1, cP = X@W1[D:], Y = X@Wg.
// grid 193: blocks 0-191 = 64 rowtiles x 3 matrices; 192 zeroes deg.
// ---------------------------------------------------------------------------
__global__ __launch_bounds__(256) void k1_gemm(
    const float* __restrict__ X, const float* __restrict__ W1,
    const float* __restrict__ Wg, const float* __restrict__ b1,
    float* __restrict__ aP, float* __restrict__ cP, float* __restrict__ Y,
    float* __restrict__ deg) {
  const int tid = threadIdx.x;
  const int blk = blockIdx.x;
  if (blk >= 192) {
    for (int i = tid; i < NN; i += 256) deg[i] = 0.f;
    return;
  }
  __shared__ float xs[16 * 256];   // 16 KB, [row][d]
  __shared__ float ws[64 * 128];   // 32 KB, [d][h]
  const int i0 = (blk & 63) * 16;
  const int m = blk >> 6;
  const float* W = (m == 0) ? W1 : (m == 1 ? W1 + DD * HH : Wg);
  const float* Xbase = X + i0 * DD;  // contiguous 16 KB
#pragma unroll
  for (int v = 0; v < 4; ++v) {
    const int fi = (v * 256 + tid) * 4;
    *(float4*)(xs + fi) = *(const float4*)(Xbase + fi);
  }
  const int tx = tid & 31, ty = tid >> 5;  // cols tx*4..+3, rows ty*2..+1
  float4 acc0 = make_float4(0.f, 0.f, 0.f, 0.f);
  float4 acc1 = make_float4(0.f, 0.f, 0.f, 0.f);
  for (int c = 0; c < 4; ++c) {
    __syncthreads();
    const float* Wbase = W + c * 64 * HH;  // contiguous 32 KB chunk
#pragma unroll
    for (int v = 0; v < 8; ++v) {
      const int fi = (v * 256 + tid) * 4;
      *(float4*)(ws + fi) = *(const float4*)(Wbase + fi);
    }
    __syncthreads();
    const float* xr0 = xs + (ty * 2) * 256 + c * 64;
    const float* xr1 = xs + (ty * 2 + 1) * 256 + c * 64;
#pragma unroll 4
    for (int d = 0; d < 64; d += 4) {
      const float4 x0 = *(const float4*)(xr0 + d);
      const float4 x1 = *(const float4*)(xr1 + d);
      const float4 w0 = *(const float4*)(ws + (d + 0) * 128 + tx * 4);
      const float4 w1 = *(const float4*)(ws + (d + 1) * 128 + tx * 4);
      const float4 w2 = *(const float4*)(ws + (d + 2) * 128 + tx * 4);
      const float4 w3 = *(const float4*)(ws + (d + 3) * 128 + tx * 4);
      acc0.x = fmaf(x0.x, w0.x, acc0.x); acc0.y = fmaf(x0.x, w0.y, acc0.y);
      acc0.z = fmaf(x0.x, w0.z, acc0.z); acc0.w = fmaf(x0.x, w0.w, acc0.w);
      acc1.x = fmaf(x1.x, w0.x, acc1.x); acc1.y = fmaf(x1.x, w0.y, acc1.y);
      acc1.z = fmaf(x1.x, w0.z, acc1.z); acc1.w = fmaf(x1.x, w0.w, acc1.w);
      acc0.x = fmaf(x0.y, w1.x, acc0.x); acc0.y = fmaf(x0.y, w1.y, acc0.y);
      acc0.z = fmaf(x0.y, w1.z, acc0.z); acc0.w = fmaf(x0.y, w1.w, acc0.w);
      acc1.x = fmaf(x1.y, w1.x, acc1.x); acc1.y = fmaf(x1.y, w1.y, acc1.y);
      acc1.z = fmaf(x1.y, w1.z, acc1.z); acc1.w = fmaf(x1.y, w1.w, acc1.w);
      acc0.x = fmaf(x0.z, w2.x, acc0.x); acc0.y = fmaf(x0.z, w2.y, acc0.y);
      acc0.z = fmaf(x0.z, w2.z, acc0.z); acc0.w = fmaf(x0.z, w2.w, acc0.w);
      acc1.x = fmaf(x1.z, w2.x, acc1.x); acc1.y = fmaf(x1.z, w2.y, acc1.y);
      acc1.z = fmaf(x1.z, w2.z, acc1.z); acc1.w = fmaf(x1.z, w2.w, acc1.w);
      acc0.x = fmaf(x0.w, w3.x, acc0.x); acc0.y = fmaf(x0.w, w3.y, acc0.y);
      acc0.z = fmaf(x0.w, w3.z, acc0.z); acc0.w = fmaf(x0.w, w3.w, acc0.w);
      acc1.x = fmaf(x1.w, w3.x, acc1.x); acc1.y = fmaf(x1.w, w3.y, acc1.y);
      acc1.z = fmaf(x1.w, w3.z, acc1.z); acc1.w = fmaf(x1.w, w3.w, acc1.w);
    }
  }
  float* dst = (m == 0) ? aP : (m == 1 ? cP : Y);
  if (m == 0) {
    const float4 bv = *(const float4*)(b1 + tx * 4);
    acc0.x += bv.x; acc0.y += bv.y; acc0.z += bv.z; acc0.w += bv.w;
    acc1.x += bv.x; acc1.y += bv.y; acc1.z += bv.z; acc1.w += bv.w;
  }
  const int r0 = i0 + ty * 2;
  *(float4*)(dst + r0 * HH + tx * 4) = acc0;
  *(float4*)(dst + (r0 + 1) * HH + tx * 4) = acc1;
}

// ---------------------------------------------------------------------------
// K2: pairwise sim -> symmetric A (diag=1) with FUSED degree accumulation.
// grid 528 = linearized upper-triangle 32x32 tiles; block 256, 2x2 per thread.
// (VALU-floor bound: 3 ops per (pair,h) — unchanged.)
// ---------------------------------------------------------------------------
__global__ __launch_bounds__(256) void k2_pairwise(
    const float* __restrict__ aP, const float* __restrict__ cP,
    const float* __restrict__ W2, const float* __restrict__ b2,
    float* __restrict__ A, float* __restrict__ deg) {
  __shared__ float as[32 * 132];
  __shared__ float cs[32 * 132];
  __shared__ float es[32 * 33];
  __shared__ float ws2[128];
  const int tid = threadIdx.x;
  // Linear tile id -> (ti, tj), ti <= tj.
  int tt = blockIdx.x, ti = 0;
  while (tt >= 32 - ti) { tt -= 32 - ti; ++ti; }
  const int tj = ti + tt;
  const int i0 = ti * 32, j0 = tj * 32;
  if (tid < 32) *(float4*)(ws2 + tid * 4) = *(const float4*)(W2 + tid * 4);
  for (int idx = tid; idx < 32 * HH; idx += 256) {
    const int row = idx >> 7, col = idx & 127;
    as[row * 132 + col] = aP[(i0 + row) * HH + col];
    cs[row * 132 + col] = cP[(j0 + row) * HH + col];
  }
  __syncthreads();
  const int li0 = (tid >> 4) * 2, lj0 = (tid & 15) * 2;
  float s00 = 0.f, s01 = 0.f, s10 = 0.f, s11 = 0.f;
#pragma unroll 8
  for (int h = 0; h < HH; h += 4) {
    const float4 a0 = *(const float4*)(as + li0 * 132 + h);
    const float4 a1 = *(const float4*)(as + (li0 + 1) * 132 + h);
    const float4 c0 = *(const float4*)(cs + lj0 * 132 + h);
    const float4 c1 = *(const float4*)(cs + (lj0 + 1) * 132 + h);
    const float4 w = *(const float4*)(ws2 + h);
    s00 += fmaxf(a0.x + c0.x, 0.f) * w.x + fmaxf(a0.y + c0.y, 0.f) * w.y +
           fmaxf(a0.z + c0.z, 0.f) * w.z + fmaxf(a0.w + c0.w, 0.f) * w.w;
    s01 += fmaxf(a0.x + c1.x, 0.f) * w.x + fmaxf(a0.y + c1.y, 0.f) * w.y +
           fmaxf(a0.z + c1.z, 0.f) * w.z + fmaxf(a0.w + c1.w, 0.f) * w.w;
    s10 += fmaxf(a1.x + c0.x, 0.f) * w.x + fmaxf(a1.y + c0.y, 0.f) * w.y +
           fmaxf(a1.z + c0.z, 0.f) * w.z + fmaxf(a1.w + c0.w, 0.f) * w.w;
    s11 += fmaxf(a1.x + c1.x, 0.f) * w.x + fmaxf(a1.y + c1.y, 0.f) * w.y +
           fmaxf(a1.z + c1.z, 0.f) * w.z + fmaxf(a1.w + c1.w, 0.f) * w.w;
  }
  const float b2v = b2[0];
  auto edge = [b2v](float s) {
    s += b2v;
    return s > 0.f ? 1.f / (1.f + __expf(-s)) : 0.f;  // sigmoid>0.5 <=> s>0
  };
  es[(li0 + 0) * 33 + lj0 + 0] = edge(s00);
  es[(li0 + 0) * 33 + lj0 + 1] = edge(s01);
  es[(li0 + 1) * 33 + lj0 + 0] = edge(s10);
  es[(li0 + 1) * 33 + lj0 + 1] = edge(s11);
  __syncthreads();
  if (ti == tj) {  // finalize diagonal tile: diag=1, mirror upper into lower
    float f[2][2];
#pragma unroll
    for (int r = 0; r < 2; ++r)
#pragma unroll
      for (int c = 0; c < 2; ++c) {
        const int li = li0 + r, lj = lj0 + c;
        f[r][c] =
            (li == lj) ? 1.f : (li < lj ? es[li * 33 + lj] : es[lj * 33 + li]);
      }
    __syncthreads();
    es[(li0 + 0) * 33 + lj0 + 0] = f[0][0];
    es[(li0 + 0) * 33 + lj0 + 1] = f[0][1];
    es[(li0 + 1) * 33 + lj0 + 0] = f[1][0];
    es[(li0 + 1) * 33 + lj0 + 1] = f[1][1];
    __syncthreads();
  }
  // Fused degree: row sums -> deg[i0+..]; col sums -> deg[j0+..] (off-diag).
  if (tid < 32) {
    float s = 0.f;
#pragma unroll
    for (int c = 0; c < 32; ++c) s += es[tid * 33 + c];
    atomicAdd(deg + i0 + tid, s);
  } else if (tid < 64 && ti != tj) {
    const int c = tid - 32;
    float s = 0.f;
#pragma unroll
    for (int r = 0; r < 32; ++r) s += es[r * 33 + c];
    atomicAdd(deg + j0 + c, s);
  }
  // Write A (+ mirror for off-diagonal), rows coalesced.
#pragma unroll
  for (int r = 0; r < 2; ++r)
#pragma unroll
    for (int c = 0; c < 2; ++c) {
      const int li = li0 + r, lj = lj0 + c;
      A[(i0 + li) * NN + j0 + lj] = es[li * 33 + lj];
      if (ti != tj) A[(j0 + li) * NN + i0 + lj] = es[lj * 33 + li];
    }
}

// ---------------------------------------------------------------------------
// K3: partial SpMM. grid 256 = 128 rowblocks (8 rows) x 2 j-halves (512 cols).
//  - Halves the per-CU L2 read of Y (256 KB/block vs 512 KB) -> phase C now
//    balanced against its own FMA stream (~4.3K cy vs old 9.1K cy L2-bound).
//  - A staged with coalesced per-row scalar loads into Ast[j][12] (pad-12):
//    the two b128 stores per j spread perfectly over all 32 banks (8 wd/bank),
//    eliminating the old 32-way transpose-store conflict (~1.7 us/block).
//  - dis[j] folded at stage time, dis[i] at writeout; partial written
//    TRANSPOSED (P[h][i]) with plain stores -> K4 reads coalesced. No atomics.
// ---------------------------------------------------------------------------
__global__ __launch_bounds__(256) void k3_spmm(
    const float* __restrict__ A, const float* __restrict__ Y,
    const float* __restrict__ deg, float* __restrict__ P0,
    float* __restrict__ P1) {
  __shared__ float Ast[512 * 12];    // 24.6 KB: [j][0..7]=A[i0+r][j]*dis[j], pad 12
  __shared__ float disl[NN];         // 4 KB: rsqrt(deg)
  __shared__ float red[8 * 1032];    // 33 KB: [ty][row*128+h], pad 8
  const int tid = threadIdx.x;
  const int rb = blockIdx.x >> 1, half = blockIdx.x & 1;
  const int i0 = rb * 8, jh0 = half * 512;
  float* __restrict__ P = half ? P1 : P0;
  // Phase A: dis = rsqrt(deg) into LDS.
  {
    const float4 dv = *(const float4*)(deg + tid * 4);
    float4 r;
    r.x = rsqrtf(dv.x); r.y = rsqrtf(dv.y);
    r.z = rsqrtf(dv.z); r.w = rsqrtf(dv.w);
    *(float4*)(disl + tid * 4) = r;
  }
  __syncthreads();
  // Phase B: stage A columns. Per-row loads are lane-coalesced; the two
  // float4 LDS stores per j hit all 32 banks evenly (12-word row pitch).
#pragma unroll
  for (int v = 0; v < 2; ++v) {
    const int jj = v * 256 + tid;        // 0..511 local col
    const int jg = jh0 + jj;             // global col
    const float d = disl[jg];
    float a[8];
#pragma unroll
    for (int r = 0; r < 8; ++r) a[r] = A[(i0 + r) * NN + jg] * d;
    *(float4*)(Ast + jj * 12)     = make_float4(a[0], a[1], a[2], a[3]);
    *(float4*)(Ast + jj * 12 + 4) = make_float4(a[4], a[5], a[6], a[7]);
  }
  __syncthreads();
  // Phase C: acc[r] = partial of row i0+r over this block's j-slice.
  // Ast reads are wave-broadcast (address depends only on ty); Y is coalesced.
  const int tx = tid & 31, ty = tid >> 5;
  const int jj0 = ty * 64;
  float4 acc[8];
#pragma unroll
  for (int r = 0; r < 8; ++r) acc[r] = make_float4(0.f, 0.f, 0.f, 0.f);
  const float* Yb = Y + (jh0 + jj0) * HH + tx * 4;
#define FMA4(AC, S) \
  AC.x = fmaf(S, yv.x, AC.x); AC.y = fmaf(S, yv.y, AC.y); \
  AC.z = fmaf(S, yv.z, AC.z); AC.w = fmaf(S, yv.w, AC.w);
#pragma unroll 4
  for (int jj = 0; jj < 64; ++jj) {
    const float4 yv = *(const float4*)(Yb + jj * HH);
    const float4 lo = *(const float4*)(Ast + (jj0 + jj) * 12);
    const float4 hi = *(const float4*)(Ast + (jj0 + jj) * 12 + 4);
    FMA4(acc[0], lo.x) FMA4(acc[1], lo.y) FMA4(acc[2], lo.z) FMA4(acc[3], lo.w)
    FMA4(acc[4], hi.x) FMA4(acc[5], hi.y) FMA4(acc[6], hi.z) FMA4(acc[7], hi.w)
  }
#undef FMA4
  // Phase D: reduce the 8 ty-slices, scale by dis[i], write transposed partial.
#pragma unroll
  for (int r = 0; r < 8; ++r)
    *(float4*)(red + ty * 1032 + r * 128 + tx * 4) = acc[r];
  __syncthreads();
  const int h = tid & 127, rg = tid >> 7;  // rows rg, rg+2, rg+4, rg+6
  float* Pcol = P + h * NN + i0;
#pragma unroll
  for (int k = 0; k < 4; ++k) {
    const int row = rg + 2 * k;
    float v = 0.f;
#pragma unroll
    for (int t = 0; t < 8; ++t) v += red[t * 1032 + row * 128 + h];
    Pcol[row] = v * disl[i0 + row];
  }
}

// ---------------------------------------------------------------------------
// K4: combine partials + BatchNorm (batch stats, biased var) + ReLU.
// grid 128 = one block per feature column h; P is [H][N] so the 1024-row
// column read is fully coalesced (one float4 per thread per partial buffer).
// Stats reduced in-block (shfl + LDS); out written strided (L2-absorbed).
// ---------------------------------------------------------------------------
__global__ __launch_bounds__(256) void k4_bn(
    const float* __restrict__ P0, const float* __restrict__ P1,
    const float* __restrict__ bg, const float* __restrict__ gamma,
    const float* __restrict__ beta, float* __restrict__ out) {
  const int tid = threadIdx.x, h = blockIdx.x;
  const float bgv = bg[h];
  const float4 p0 = *(const float4*)(P0 + h * NN + tid * 4);
  const float4 p1 = *(const float4*)(P1 + h * NN + tid * 4);
  float v[4] = {p0.x + p1.x + bgv, p0.y + p1.y + bgv,
                p0.z + p1.z + bgv, p0.w + p1.w + bgv};
  float s1 = v[0] + v[1] + v[2] + v[3];
  float s2 = v[0] * v[0] + v[1] * v[1] + v[2] * v[2] + v[3] * v[3];
  __shared__ float rs1[4], rs2[4], msh[2];
#pragma unroll
  for (int off = 32; off; off >>= 1) {
    s1 += __shfl_down(s1, off);
    s2 += __shfl_down(s2, off);
  }
  if ((tid & 63) == 0) { rs1[tid >> 6] = s1; rs2[tid >> 6] = s2; }
  __syncthreads();
  if (tid == 0) {
    const float t1 = rs1[0] + rs1[1] + rs1[2] + rs1[3];
    const float t2 = rs2[0] + rs2[1] + rs2[2] + rs2[3];
    const float mean = t1 * (1.f / NN);
    const float var = t2 * (1.f / NN) - mean * mean;
    msh[0] = mean;
    msh[1] = rsqrtf(var + BN_EPS);
  }
  __syncthreads();
  const float mean = msh[0], rinv = msh[1];
  const float g = gamma[h], be = beta[h];
#pragma unroll
  for (int k = 0; k < 4; ++k) {
    const float val = g * (v[k] - mean) * rinv + be;
    out[(tid * 4 + k) * HH + h] = fmaxf(val, 0.f);
  }
}

// ---------------------------------------------------------------------------
extern "C" void kernel_launch(void* const* d_in, const int* in_sizes, int n_in,
                              void* d_out, int out_size, void* d_ws,
                              size_t ws_size, hipStream_t stream) {
  const float* X = (const float*)d_in[0];
  const float* W1 = (const float*)d_in[1];
  const float* b1 = (const float*)d_in[2];
  const float* W2 = (const float*)d_in[3];
  const float* b2 = (const float*)d_in[4];
  const float* Wg = (const float*)d_in[5];
  const float* bg = (const float*)d_in[6];
  const float* gamma = (const float*)d_in[7];
  const float* beta = (const float*)d_in[8];
  float* out = (float*)d_out;

  float* w = (float*)d_ws;
  float* A = w + OFF_A;
  float* aP = w + OFF_AP;
  float* cP = w + OFF_CP;
  float* Y = w + OFF_Y;
  float* deg = w + OFF_DEG;
  float* P0 = w + OFF_P0;
  float* P1 = w + OFF_P1;

  k1_gemm<<<dim3(193), 256, 0, stream>>>(X, W1, Wg, b1, aP, cP, Y, deg);
  k2_pairwise<<<dim3(528), 256, 0, stream>>>(aP, cP, W2, b2, A, deg);
  k3_spmm<<<dim3(256), 256, 0, stream>>>(A, Y, deg, P0, P1);
  k4_bn<<<dim3(128), 256, 0, stream>>>(P0, P1, bg, gamma, beta, out);
}

// Round 3
// 110.170 us; speedup vs baseline: 1.0662x; 1.0071x over previous
//
#include <hip/hip_runtime.h>
#include <math.h>

// Problem constants
constexpr int NN = 1024;   // nodes
constexpr int DD = 256;    // embedding dim
constexpr int HH = 128;    // hidden dim
constexpr float BN_EPS = 1e-5f;

// Workspace layout (in floats)
constexpr int OFF_A      = 0;                          // [1024 x 1024] adjacency
constexpr int OFF_AP     = OFF_A + NN * NN;            // [N x H] a + b1
constexpr int OFF_CP     = OFF_AP + NN * HH;           // [N x H] c
constexpr int OFF_Y      = OFF_CP + NN * HH;           // [N x H] X@Wg
constexpr int OFF_DEG    = OFF_Y + NN * HH;            // [N] degree accumulators
constexpr int OFF_P0     = OFF_DEG + NN;               // [H x N] partial (j-half 0), TRANSPOSED
constexpr int OFF_P1     = OFF_P0 + NN * HH;           // [H x N] partial (j-half 1), TRANSPOSED

// ---------------------------------------------------------------------------
// K1: fused GEMMs  aP = X@W1[:D]+b1, cP = X@W1[D:], Y = X@Wg.
// grid 193: blocks 0-191 = 64 rowtiles x 3 matrices; 192 zeroes deg.
// (verified R1 body, unchanged)
// ---------------------------------------------------------------------------
__global__ __launch_bounds__(256) void k1_gemm(
    const float* __restrict__ X, const float* __restrict__ W1,
    const float* __restrict__ Wg, const float* __restrict__ b1,
    float* __restrict__ aP, float* __restrict__ cP, float* __restrict__ Y,
    float* __restrict__ deg) {
  const int tid = threadIdx.x;
  const int blk = blockIdx.x;
  if (blk >= 192) {
    for (int i = tid; i < NN; i += 256) deg[i] = 0.f;
    return;
  }
  __shared__ float xs[16 * 256];   // 16 KB, [row][d]
  __shared__ float ws[64 * 128];   // 32 KB, [d][h]
  const int i0 = (blk & 63) * 16;
  const int m = blk >> 6;
  const float* W = (m == 0) ? W1 : (m == 1 ? W1 + DD * HH : Wg);
  const float* Xbase = X + i0 * DD;  // contiguous 16 KB
#pragma unroll
  for (int v = 0; v < 4; ++v) {
    const int fi = (v * 256 + tid) * 4;
    *(float4*)(xs + fi) = *(const float4*)(Xbase + fi);
  }
  const int tx = tid & 31, ty = tid >> 5;  // cols tx*4..+3, rows ty*2..+1
  float4 acc0 = make_float4(0.f, 0.f, 0.f, 0.f);
  float4 acc1 = make_float4(0.f, 0.f, 0.f, 0.f);
  for (int c = 0; c < 4; ++c) {
    __syncthreads();
    const float* Wbase = W + c * 64 * HH;  // contiguous 32 KB chunk
#pragma unroll
    for (int v = 0; v < 8; ++v) {
      const int fi = (v * 256 + tid) * 4;
      *(float4*)(ws + fi) = *(const float4*)(Wbase + fi);
    }
    __syncthreads();
    const float* xr0 = xs + (ty * 2) * 256 + c * 64;
    const float* xr1 = xs + (ty * 2 + 1) * 256 + c * 64;
#pragma unroll 4
    for (int d = 0; d < 64; d += 4) {
      const float4 x0 = *(const float4*)(xr0 + d);
      const float4 x1 = *(const float4*)(xr1 + d);
      const float4 w0 = *(const float4*)(ws + (d + 0) * 128 + tx * 4);
      const float4 w1 = *(const float4*)(ws + (d + 1) * 128 + tx * 4);
      const float4 w2 = *(const float4*)(ws + (d + 2) * 128 + tx * 4);
      const float4 w3 = *(const float4*)(ws + (d + 3) * 128 + tx * 4);
      acc0.x = fmaf(x0.x, w0.x, acc0.x); acc0.y = fmaf(x0.x, w0.y, acc0.y);
      acc0.z = fmaf(x0.x, w0.z, acc0.z); acc0.w = fmaf(x0.x, w0.w, acc0.w);
      acc1.x = fmaf(x1.x, w0.x, acc1.x); acc1.y = fmaf(x1.x, w0.y, acc1.y);
      acc1.z = fmaf(x1.x, w0.z, acc1.z); acc1.w = fmaf(x1.x, w0.w, acc1.w);
      acc0.x = fmaf(x0.y, w1.x, acc0.x); acc0.y = fmaf(x0.y, w1.y, acc0.y);
      acc0.z = fmaf(x0.y, w1.z, acc0.z); acc0.w = fmaf(x0.y, w1.w, acc0.w);
      acc1.x = fmaf(x1.y, w1.x, acc1.x); acc1.y = fmaf(x1.y, w1.y, acc1.y);
      acc1.z = fmaf(x1.y, w1.z, acc1.z); acc1.w = fmaf(x1.y, w1.w, acc1.w);
      acc0.x = fmaf(x0.z, w2.x, acc0.x); acc0.y = fmaf(x0.z, w2.y, acc0.y);
      acc0.z = fmaf(x0.z, w2.z, acc0.z); acc0.w = fmaf(x0.z, w2.w, acc0.w);
      acc1.x = fmaf(x1.z, w2.x, acc1.x); acc1.y = fmaf(x1.z, w2.y, acc1.y);
      acc1.z = fmaf(x1.z, w2.z, acc1.z); acc1.w = fmaf(x1.z, w2.w, acc1.w);
      acc0.x = fmaf(x0.w, w3.x, acc0.x); acc0.y = fmaf(x0.w, w3.y, acc0.y);
      acc0.z = fmaf(x0.w, w3.z, acc0.z); acc0.w = fmaf(x0.w, w3.w, acc0.w);
      acc1.x = fmaf(x1.w, w3.x, acc1.x); acc1.y = fmaf(x1.w, w3.y, acc1.y);
      acc1.z = fmaf(x1.w, w3.z, acc1.z); acc1.w = fmaf(x1.w, w3.w, acc1.w);
    }
  }
  float* dst = (m == 0) ? aP : (m == 1 ? cP : Y);
  if (m == 0) {
    const float4 bv = *(const float4*)(b1 + tx * 4);
    acc0.x += bv.x; acc0.y += bv.y; acc0.z += bv.z; acc0.w += bv.w;
    acc1.x += bv.x; acc1.y += bv.y; acc1.z += bv.z; acc1.w += bv.w;
  }
  const int r0 = i0 + ty * 2;
  *(float4*)(dst + r0 * HH + tx * 4) = acc0;
  *(float4*)(dst + (r0 + 1) * HH + tx * 4) = acc1;
}

// ---------------------------------------------------------------------------
// K2: pairwise sim -> symmetric A (diag=1) with FUSED degree accumulation.
// grid 528 upper-triangle 32x32 tiles; NEW: block 128, 2 rows x 4 cols per
// thread. LDS reads per h4-chunk: 7 b128 for 8 outputs (was 5 for 4) ->
// 1.43x less LDS traffic; c-reads are 8 contiguous float4 groups (ideal
// dedup). 38.5 KB LDS -> 4 blocks/CU: all 528 blocks co-resident.
// Staging vectorized to float4. Accumulation order per output unchanged.
// ---------------------------------------------------------------------------
__global__ __launch_bounds__(128) void k2_pairwise(
    const float* __restrict__ aP, const float* __restrict__ cP,
    const float* __restrict__ W2, const float* __restrict__ b2,
    float* __restrict__ A, float* __restrict__ deg) {
  __shared__ float as[32 * 132];
  __shared__ float cs[32 * 132];
  __shared__ float es[32 * 33];
  __shared__ float ws2[128];
  const int tid = threadIdx.x;
  // Linear tile id -> (ti, tj), ti <= tj.
  int tt = blockIdx.x, ti = 0;
  while (tt >= 32 - ti) { tt -= 32 - ti; ++ti; }
  const int tj = ti + tt;
  const int i0 = ti * 32, j0 = tj * 32;
  if (tid < 32) *(float4*)(ws2 + tid * 4) = *(const float4*)(W2 + tid * 4);
  // Stage: 1024 float4 per matrix over 128 threads = 8 each, coalesced.
#pragma unroll
  for (int v = 0; v < 8; ++v) {
    const int f = v * 128 + tid;          // float4 index 0..1023
    const int row = f >> 5, c4 = (f & 31) * 4;
    *(float4*)(as + row * 132 + c4) = *(const float4*)(aP + (i0 + row) * HH + c4);
    *(float4*)(cs + row * 132 + c4) = *(const float4*)(cP + (j0 + row) * HH + c4);
  }
  __syncthreads();
  const int li0 = (tid >> 3) * 2;      // rows li0, li0+1   (16 row-groups)
  const int lj0 = (tid & 7) * 4;       // cols lj0..lj0+3   (8 col-groups)
  float s[2][4] = {};
#pragma unroll 4
  for (int h = 0; h < HH; h += 4) {
    const float4 a0 = *(const float4*)(as + li0 * 132 + h);
    const float4 a1 = *(const float4*)(as + (li0 + 1) * 132 + h);
    const float4 w = *(const float4*)(ws2 + h);
#pragma unroll
    for (int c = 0; c < 4; ++c) {
      const float4 cc = *(const float4*)(cs + (lj0 + c) * 132 + h);
      s[0][c] += fmaxf(a0.x + cc.x, 0.f) * w.x + fmaxf(a0.y + cc.y, 0.f) * w.y +
                 fmaxf(a0.z + cc.z, 0.f) * w.z + fmaxf(a0.w + cc.w, 0.f) * w.w;
      s[1][c] += fmaxf(a1.x + cc.x, 0.f) * w.x + fmaxf(a1.y + cc.y, 0.f) * w.y +
                 fmaxf(a1.z + cc.z, 0.f) * w.z + fmaxf(a1.w + cc.w, 0.f) * w.w;
    }
  }
  const float b2v = b2[0];
  auto edge = [b2v](float s) {
    s += b2v;
    return s > 0.f ? 1.f / (1.f + __expf(-s)) : 0.f;  // sigmoid>0.5 <=> s>0
  };
#pragma unroll
  for (int c = 0; c < 4; ++c) {
    es[(li0 + 0) * 33 + lj0 + c] = edge(s[0][c]);
    es[(li0 + 1) * 33 + lj0 + c] = edge(s[1][c]);
  }
  __syncthreads();
  if (ti == tj) {  // finalize diagonal tile: diag=1, mirror upper into lower
    float f[2][4];
#pragma unroll
    for (int r = 0; r < 2; ++r)
#pragma unroll
      for (int c = 0; c < 4; ++c) {
        const int li = li0 + r, lj = lj0 + c;
        f[r][c] =
            (li == lj) ? 1.f : (li < lj ? es[li * 33 + lj] : es[lj * 33 + li]);
      }
    __syncthreads();
#pragma unroll
    for (int r = 0; r < 2; ++r)
#pragma unroll
      for (int c = 0; c < 4; ++c)
        es[(li0 + r) * 33 + lj0 + c] = f[r][c];
    __syncthreads();
  }
  // Fused degree: row sums -> deg[i0+..]; col sums -> deg[j0+..] (off-diag).
  if (tid < 32) {
    float s = 0.f;
#pragma unroll
    for (int c = 0; c < 32; ++c) s += es[tid * 33 + c];
    atomicAdd(deg + i0 + tid, s);
  } else if (tid < 64 && ti != tj) {
    const int c = tid - 32;
    float s = 0.f;
#pragma unroll
    for (int r = 0; r < 32; ++r) s += es[r * 33 + c];
    atomicAdd(deg + j0 + c, s);
  }
  // Write A (+ mirror for off-diagonal).
#pragma unroll
  for (int r = 0; r < 2; ++r)
#pragma unroll
    for (int c = 0; c < 4; ++c) {
      const int li = li0 + r, lj = lj0 + c;
      A[(i0 + li) * NN + j0 + lj] = es[li * 33 + lj];
      if (ti != tj) A[(j0 + li) * NN + i0 + lj] = es[lj * 33 + li];
    }
}

// ---------------------------------------------------------------------------
// K3: partial SpMM. grid 256 = 128 rowblocks (8 rows) x 2 j-halves (512 cols).
// (verified R1 body, unchanged)
// ---------------------------------------------------------------------------
__global__ __launch_bounds__(256) void k3_spmm(
    const float* __restrict__ A, const float* __restrict__ Y,
    const float* __restrict__ deg, float* __restrict__ P0,
    float* __restrict__ P1) {
  __shared__ float Ast[512 * 12];    // 24.6 KB: [j][0..7]=A[i0+r][j]*dis[j], pad 12
  __shared__ float disl[NN];         // 4 KB: rsqrt(deg)
  __shared__ float red[8 * 1032];    // 33 KB: [ty][row*128+h], pad 8
  const int tid = threadIdx.x;
  const int rb = blockIdx.x >> 1, half = blockIdx.x & 1;
  const int i0 = rb * 8, jh0 = half * 512;
  float* __restrict__ P = half ? P1 : P0;
  // Phase A: dis = rsqrt(deg) into LDS.
  {
    const float4 dv = *(const float4*)(deg + tid * 4);
    float4 r;
    r.x = rsqrtf(dv.x); r.y = rsqrtf(dv.y);
    r.z = rsqrtf(dv.z); r.w = rsqrtf(dv.w);
    *(float4*)(disl + tid * 4) = r;
  }
  __syncthreads();
  // Phase B: stage A columns. Per-row loads are lane-coalesced; the two
  // float4 LDS stores per j hit all 32 banks evenly (12-word row pitch).
#pragma unroll
  for (int v = 0; v < 2; ++v) {
    const int jj = v * 256 + tid;        // 0..511 local col
    const int jg = jh0 + jj;             // global col
    const float d = disl[jg];
    float a[8];
#pragma unroll
    for (int r = 0; r < 8; ++r) a[r] = A[(i0 + r) * NN + jg] * d;
    *(float4*)(Ast + jj * 12)     = make_float4(a[0], a[1], a[2], a[3]);
    *(float4*)(Ast + jj * 12 + 4) = make_float4(a[4], a[5], a[6], a[7]);
  }
  __syncthreads();
  // Phase C: acc[r] = partial of row i0+r over this block's j-slice.
  const int tx = tid & 31, ty = tid >> 5;
  const int jj0 = ty * 64;
  float4 acc[8];
#pragma unroll
  for (int r = 0; r < 8; ++r) acc[r] = make_float4(0.f, 0.f, 0.f, 0.f);
  const float* Yb = Y + (jh0 + jj0) * HH + tx * 4;
#define FMA4(AC, S) \
  AC.x = fmaf(S, yv.x, AC.x); AC.y = fmaf(S, yv.y, AC.y); \
  AC.z = fmaf(S, yv.z, AC.z); AC.w = fmaf(S, yv.w, AC.w);
#pragma unroll 4
  for (int jj = 0; jj < 64; ++jj) {
    const float4 yv = *(const float4*)(Yb + jj * HH);
    const float4 lo = *(const float4*)(Ast + (jj0 + jj) * 12);
    const float4 hi = *(const float4*)(Ast + (jj0 + jj) * 12 + 4);
    FMA4(acc[0], lo.x) FMA4(acc[1], lo.y) FMA4(acc[2], lo.z) FMA4(acc[3], lo.w)
    FMA4(acc[4], hi.x) FMA4(acc[5], hi.y) FMA4(acc[6], hi.z) FMA4(acc[7], hi.w)
  }
#undef FMA4
  // Phase D: reduce the 8 ty-slices, scale by dis[i], write transposed partial.
#pragma unroll
  for (int r = 0; r < 8; ++r)
    *(float4*)(red + ty * 1032 + r * 128 + tx * 4) = acc[r];
  __syncthreads();
  const int h = tid & 127, rg = tid >> 7;  // rows rg, rg+2, rg+4, rg+6
  float* Pcol = P + h * NN + i0;
#pragma unroll
  for (int k = 0; k < 4; ++k) {
    const int row = rg + 2 * k;
    float v = 0.f;
#pragma unroll
    for (int t = 0; t < 8; ++t) v += red[t * 1032 + row * 128 + h];
    Pcol[row] = v * disl[i0 + row];
  }
}

// ---------------------------------------------------------------------------
// K4: combine partials + BatchNorm (batch stats, biased var) + ReLU.
// (verified R1 body, unchanged)
// ---------------------------------------------------------------------------
__global__ __launch_bounds__(256) void k4_bn(
    const float* __restrict__ P0, const float* __restrict__ P1,
    const float* __restrict__ bg, const float* __restrict__ gamma,
    const float* __restrict__ beta, float* __restrict__ out) {
  const int tid = threadIdx.x, h = blockIdx.x;
  const float bgv = bg[h];
  const float4 p0 = *(const float4*)(P0 + h * NN + tid * 4);
  const float4 p1 = *(const float4*)(P1 + h * NN + tid * 4);
  float v[4] = {p0.x + p1.x + bgv, p0.y + p1.y + bgv,
                p0.z + p1.z + bgv, p0.w + p1.w + bgv};
  float s1 = v[0] + v[1] + v[2] + v[3];
  float s2 = v[0] * v[0] + v[1] * v[1] + v[2] * v[2] + v[3] * v[3];
  __shared__ float rs1[4], rs2[4], msh[2];
#pragma unroll
  for (int off = 32; off; off >>= 1) {
    s1 += __shfl_down(s1, off);
    s2 += __shfl_down(s2, off);
  }
  if ((tid & 63) == 0) { rs1[tid >> 6] = s1; rs2[tid >> 6] = s2; }
  __syncthreads();
  if (tid == 0) {
    const float t1 = rs1[0] + rs1[1] + rs1[2] + rs1[3];
    const float t2 = rs2[0] + rs2[1] + rs2[2] + rs2[3];
    const float mean = t1 * (1.f / NN);
    const float var = t2 * (1.f / NN) - mean * mean;
    msh[0] = mean;
    msh[1] = rsqrtf(var + BN_EPS);
  }
  __syncthreads();
  const float mean = msh[0], rinv = msh[1];
  const float g = gamma[h], be = beta[h];
#pragma unroll
  for (int k = 0; k < 4; ++k) {
    const float val = g * (v[k] - mean) * rinv + be;
    out[(tid * 4 + k) * HH + h] = fmaxf(val, 0.f);
  }
}

// ---------------------------------------------------------------------------
extern "C" void kernel_launch(void* const* d_in, const int* in_sizes, int n_in,
                              void* d_out, int out_size, void* d_ws,
                              size_t ws_size, hipStream_t stream) {
  const float* X = (const float*)d_in[0];
  const float* W1 = (const float*)d_in[1];
  const float* b1 = (const float*)d_in[2];
  const float* W2 = (const float*)d_in[3];
  const float* b2 = (const float*)d_in[4];
  const float* Wg = (const float*)d_in[5];
  const float* bg = (const float*)d_in[6];
  const float* gamma = (const float*)d_in[7];
  const float* beta = (const float*)d_in[8];
  float* out = (float*)d_out;

  float* w = (float*)d_ws;
  float* A = w + OFF_A;
  float* aP = w + OFF_AP;
  float* cP = w + OFF_CP;
  float* Y = w + OFF_Y;
  float* deg = w + OFF_DEG;
  float* P0 = w + OFF_P0;
  float* P1 = w + OFF_P1;

  k1_gemm<<<dim3(193), 256, 0, stream>>>(X, W1, Wg, b1, aP, cP, Y, deg);
  k2_pairwise<<<dim3(528), 128, 0, stream>>>(aP, cP, W2, b2, A, deg);
  k3_spmm<<<dim3(256), 256, 0, stream>>>(A, Y, deg, P0, P1);
  k4_bn<<<dim3(128), 256, 0, stream>>>(P0, P1, bg, gamma, beta, out);
}